// Round 18
// baseline (145.656 us; speedup 1.0000x reference)
//
#include <hip/hip_runtime.h>

#define N_NODES 10000
#define BN_TOT  40000
#define HID     64
#define IN_F    16
#define TCH     32
#define NW      12
#define RSTRIDE 192   // floats per mB row: planes [t=3][ch=64] at +0B, +256B, +512B

// ---------------- histogram of dst (degree = cnt + 1) ------------------------
__global__ void hist_kernel(const int* __restrict__ dst, int* __restrict__ cnt, int E) {
    int e = blockIdx.x * blockDim.x + threadIdx.x;
    if (e < E) atomicAdd(&cnt[dst[e]], 1);
}

// ------ single-block scan, shuffle-based (1 barrier instead of 21) -----------
__global__ __launch_bounds__(1024) void scan_kernel(const int* __restrict__ cnt,
                                                    int* __restrict__ row_ptr,
                                                    int* __restrict__ fill_pos,
                                                    float* __restrict__ dinv) {
    __shared__ int wsum[16];
    int t = threadIdx.x;
    int lane = t & 63, wv = t >> 6;
    int base = t * 10;                       // 1024*10 = 10240 >= 10000
    int cl[10];
    int s = 0;
#pragma unroll
    for (int k = 0; k < 10; ++k) {
        int b = base + k;
        int c = (b < N_NODES) ? cnt[b] : 0;
        cl[k] = c; s += c;
    }
    // inclusive shuffle scan within wave
    int v = s;
#pragma unroll
    for (int off = 1; off < 64; off <<= 1) {
        int u = __shfl_up(v, off);
        if (lane >= off) v += u;
    }
    if (lane == 63) wsum[wv] = v;
    __syncthreads();
    int woff = 0;
    for (int i = 0; i < wv; ++i) woff += wsum[i];   // LDS broadcast reads
    int running = woff + v - s;                      // exclusive start of chunk
#pragma unroll
    for (int k = 0; k < 10; ++k) {
        int b = base + k;
        if (b < N_NODES) {
            row_ptr[b]  = running;
            fill_pos[b] = running;
            dinv[b] = rsqrtf((float)cl[k] + 1.0f);
            running += cl[k];
        }
    }
    if (t == 1023) row_ptr[N_NODES] = woff + v;
}

// ------ CSR bucket fill: edge record = {src*64 (byte off in x plane), ne} ----
__global__ void fill_kernel(const int* __restrict__ src, const int* __restrict__ dst,
                            const float* __restrict__ dinv,
                            int* __restrict__ fill_pos,
                            int2* __restrict__ edges, int E) {
    int e = blockIdx.x * blockDim.x + threadIdx.x;
    if (e >= E) return;
    int s = src[e], d = dst[e];
    int pos = atomicAdd(&fill_pos[d], 1);
    edges[pos] = make_int2(s * 64, __float_as_int(dinv[s] * dinv[d]));
}

// ---------------- pack conv weights: float4 / float2 per (ic, tc) ------------
__global__ void prep_kernel(const float* __restrict__ c1w, const float* __restrict__ c2w,
                            float4* __restrict__ w1p, float2* __restrict__ w2p) {
    int idx = blockIdx.x * blockDim.x + threadIdx.x;   // 3072 threads
    if (idx < 2048) {
        int tc = idx & 31, ic = idx >> 5;
        const float* p = c1w + tc * 192 + ic * 3;
        w1p[idx] = make_float4(p[0], p[1], p[2], 0.f);
    } else {
        int i2 = idx - 2048;
        int tc = i2 & 31, ic = i2 >> 5;
        const float* p = c2w + tc * 96 + ic * 3;
        w2p[i2] = make_float2(p[0], p[1]);
    }
}

// ---- gatherX (rows < N_NODES): xagg = Σ ne·x[src] + dinv²·x[dst]  (layer-1 --
// gather pushed through W1 by linearity). Then h1 = relu(xagg@W1 + b1);
// mB = h1 @ W2. Per edge: ONE 4B/lane load (48 active lanes, 192 B) + 1 FMA.
__global__ __launch_bounds__(256, 8) void gatherX_kernel(
        const float* __restrict__ x, const int* __restrict__ row_ptr,
        const int2* __restrict__ edges, const float* __restrict__ dinv,
        const float* __restrict__ W1, const float* __restrict__ b1,
        const float* __restrict__ W2, float* __restrict__ m2) {
    __shared__ float xs[4][64];       // aggregated x; slots 0..47 used
    __shared__ float hs[4][3][HID];
    int gid = blockIdx.x * blockDim.x + threadIdx.x;   // 10000 waves
    int lane = threadIdx.x & 63;
    int wv = threadIdx.x >> 6;
    int row = __builtin_amdgcn_readfirstlane(gid >> 6);
    int tt = lane >> 4; if (tt > 2) tt = 2;            // lanes 48-63 mirror t=2
    int f = lane & 15;
    const char* xlane = (const char*)(x + (size_t)(9 + tt) * N_NODES * IN_F + f);
    float dv = dinv[row];
    float s = dv * dv * *(const float*)(xlane + row * 64);
    int j = row_ptr[row], end = row_ptr[row + 1];
    for (; j + 7 < end; j += 8) {
        int2 e0 = edges[j],     e1 = edges[j + 1], e2 = edges[j + 2], e3 = edges[j + 3];
        int2 e4 = edges[j + 4], e5 = edges[j + 5], e6 = edges[j + 6], e7 = edges[j + 7];
        float v0 = *(const float*)(xlane + e0.x);
        float v1 = *(const float*)(xlane + e1.x);
        float v2 = *(const float*)(xlane + e2.x);
        float v3 = *(const float*)(xlane + e3.x);
        float v4 = *(const float*)(xlane + e4.x);
        float v5 = *(const float*)(xlane + e5.x);
        float v6 = *(const float*)(xlane + e6.x);
        float v7 = *(const float*)(xlane + e7.x);
        s += __int_as_float(e0.y) * v0 + __int_as_float(e1.y) * v1
           + __int_as_float(e2.y) * v2 + __int_as_float(e3.y) * v3
           + __int_as_float(e4.y) * v4 + __int_as_float(e5.y) * v5
           + __int_as_float(e6.y) * v6 + __int_as_float(e7.y) * v7;
    }
    for (; j < end; ++j) {
        int2 e = edges[j];
        s += __int_as_float(e.y) * *(const float*)(xlane + e.x);
    }
    xs[wv][lane] = s;                 // lanes 48-63 write dead slots
    __builtin_amdgcn_wave_barrier();

    // ---- W1 matmul: lane = oc; h1[t][oc] = relu(Σ_f xagg[t][f]·W1[f][oc]+b1)
    float w1r[16];
#pragma unroll
    for (int ff = 0; ff < IN_F; ++ff) w1r[ff] = W1[ff * HID + lane];
    float h0 = 0.f, h1v = 0.f, h2 = 0.f;
#pragma unroll
    for (int ff = 0; ff < IN_F; ++ff) {
        float wv1 = w1r[ff];
        h0  += wv1 * xs[wv][ff];
        h1v += wv1 * xs[wv][16 + ff];
        h2  += wv1 * xs[wv][32 + ff];
    }
    float bb = b1[lane];
    hs[wv][0][lane] = fmaxf(h0 + bb, 0.f);
    hs[wv][1][lane] = fmaxf(h1v + bb, 0.f);
    hs[wv][2][lane] = fmaxf(h2 + bb, 0.f);
    __builtin_amdgcn_wave_barrier();

    // ---- W2 matmul ----
    const float4* h0v4 = (const float4*)&hs[wv][0][0];
    const float4* h1v4 = (const float4*)&hs[wv][1][0];
    const float4* h2v4 = (const float4*)&hs[wv][2][0];
    float t0 = 0.f, t1 = 0.f, t2 = 0.f;
#pragma unroll
    for (int ic4 = 0; ic4 < 16; ++ic4) {
        float4 a0 = h0v4[ic4], a1 = h1v4[ic4], a2 = h2v4[ic4];
        float wA = W2[(ic4 * 4 + 0) * HID + lane];
        float wB = W2[(ic4 * 4 + 1) * HID + lane];
        float wC = W2[(ic4 * 4 + 2) * HID + lane];
        float wD = W2[(ic4 * 4 + 3) * HID + lane];
        t0 += a0.x * wA + a0.y * wB + a0.z * wC + a0.w * wD;
        t1 += a1.x * wA + a1.y * wB + a1.z * wC + a1.w * wD;
        t2 += a2.x * wA + a2.y * wB + a2.z * wC + a2.w * wD;
    }
    float* m2r = m2 + (size_t)row * RSTRIDE;
    m2r[lane] = t0; m2r[64 + lane] = t1; m2r[128 + lane] = t2;
}

// ---- convfc: wave w handles rows {w, w+10k, w+20k, w+30k} -------------------
// Slot 0 = graph row: layer-2 gather over mB in THREE PLANE-PHASED PASSES —
// each pass touches one 2.56 MB plane (fits per-XCD L2). Accumulators are
// per-plane independent -> bit-identical to single-pass. Slots 1..3 = dense.
__global__ __launch_bounds__(512, 6) void convfc_kernel(
        const float* __restrict__ mB, const int* __restrict__ row_ptr,
        const int2* __restrict__ edges,
        const float* __restrict__ dinv, const float* __restrict__ b2,
        const float* __restrict__ x, const float* __restrict__ W1,
        const float* __restrict__ b1, const float* __restrict__ W2,
        const float4* __restrict__ w1p, const float* __restrict__ b1c,
        const float2* __restrict__ w2p, const float* __restrict__ b2c,
        const float* __restrict__ fcw, const float* __restrict__ fcb,
        float* __restrict__ out) {
    __shared__ float2 w1s01[2048];          // (k0,k1) weights  16 KB
    __shared__ float  w1s2[2048];           // k2 weights        8 KB
    __shared__ float  sm[8][768];           // hs[slot][plane][ch]; c1 aliased  24 KB
    int t = threadIdx.x;
#pragma unroll
    for (int i = 0; i < 4; ++i) {
        float4 wv4 = w1p[i * 512 + t];
        w1s01[i * 512 + t] = make_float2(wv4.x, wv4.y);
        w1s2[i * 512 + t] = wv4.z;
    }
    __syncthreads();

    int wv = t >> 6, lane = t & 63;
    int w = __builtin_amdgcn_readfirstlane(blockIdx.x * 8 + wv);   // 0..9999
    float* hsw = sm[wv];   // hs(slot,plane,ch) = hsw[slot*192 + plane*64 + ch]

    // ---- slot 0: graph row w — 3 plane-phased passes over mB ----
    {
        const char* mrow = (const char*)mB + (size_t)w * (RSTRIDE * 4);
        float dv = dinv[w];
        float sn = dv * dv;
        float bb = b2[lane];
        int j0 = row_ptr[w], end = row_ptr[w + 1];
#pragma unroll
        for (int p = 0; p < 3; ++p) {
            const int lo = p * 256 + lane * 4;
            float s = sn * *(const float*)(mrow + lo);
            int j = j0;
            for (; j + 7 < end; j += 8) {
                int2 e0 = edges[j],     e1 = edges[j + 1], e2 = edges[j + 2], e3 = edges[j + 3];
                int2 e4 = edges[j + 4], e5 = edges[j + 5], e6 = edges[j + 6], e7 = edges[j + 7];
                float v0 = *(const float*)((const char*)mB + e0.x * 12 + lo);
                float v1 = *(const float*)((const char*)mB + e1.x * 12 + lo);
                float v2 = *(const float*)((const char*)mB + e2.x * 12 + lo);
                float v3 = *(const float*)((const char*)mB + e3.x * 12 + lo);
                float v4 = *(const float*)((const char*)mB + e4.x * 12 + lo);
                float v5 = *(const float*)((const char*)mB + e5.x * 12 + lo);
                float v6 = *(const float*)((const char*)mB + e6.x * 12 + lo);
                float v7 = *(const float*)((const char*)mB + e7.x * 12 + lo);
                s += __int_as_float(e0.y) * v0 + __int_as_float(e1.y) * v1
                   + __int_as_float(e2.y) * v2 + __int_as_float(e3.y) * v3
                   + __int_as_float(e4.y) * v4 + __int_as_float(e5.y) * v5
                   + __int_as_float(e6.y) * v6 + __int_as_float(e7.y) * v7;
            }
            for (; j < end; ++j) {
                int2 e = edges[j];
                s += __int_as_float(e.y) * *(const float*)((const char*)mB + e.x * 12 + lo);
            }
            hsw[0 * 192 + p * 64 + lane] = fmaxf(s + bb, 0.f);
        }
    }

    // ---- slots 1..3: dense rows w + k*10000 (b = k), full chain from x ----
    {
        float w1r[16];
#pragma unroll
        for (int f = 0; f < IN_F; ++f) w1r[f] = W1[f * HID + lane];
        float s[9];
#pragma unroll
        for (int k = 1; k <= 3; ++k) {
#pragma unroll
            for (int tt = 0; tt < 3; ++tt) {
                const float* xp = x + ((size_t)(k * NW + 9 + tt) * N_NODES + w) * IN_F;
                float a = 0.f;
#pragma unroll
                for (int f = 0; f < IN_F; ++f) a += xp[f] * w1r[f];  // xp uniform -> s_loads
                s[(k - 1) * 3 + tt] = a;
            }
        }
        float bb1 = b1[lane];
#pragma unroll
        for (int k = 1; k <= 3; ++k) {
            hsw[k * 192 + 0 * 64 + lane] = fmaxf(s[(k - 1) * 3 + 0] + bb1, 0.f);
            hsw[k * 192 + 1 * 64 + lane] = fmaxf(s[(k - 1) * 3 + 1] + bb1, 0.f);
            hsw[k * 192 + 2 * 64 + lane] = fmaxf(s[(k - 1) * 3 + 2] + bb1, 0.f);
        }
        __builtin_amdgcn_wave_barrier();
        float acc[9];
#pragma unroll
        for (int mm = 0; mm < 9; ++mm) acc[mm] = 0.f;
#pragma unroll
        for (int k4 = 0; k4 < 16; ++k4) {
            float wA = W2[(k4 * 4 + 0) * HID + lane];
            float wB = W2[(k4 * 4 + 1) * HID + lane];
            float wC = W2[(k4 * 4 + 2) * HID + lane];
            float wD = W2[(k4 * 4 + 3) * HID + lane];
#pragma unroll
            for (int k = 1; k <= 3; ++k) {
#pragma unroll
                for (int tt = 0; tt < 3; ++tt) {
                    float4 h = ((const float4*)&hsw[k * 192 + tt * 64])[k4];  // broadcast
                    acc[(k - 1) * 3 + tt] += h.x * wA + h.y * wB + h.z * wC + h.w * wD;
                }
            }
        }
        __builtin_amdgcn_wave_barrier();
        float bb2 = b2[lane];
#pragma unroll
        for (int k = 1; k <= 3; ++k) {
            hsw[k * 192 + 0 * 64 + lane] = fmaxf(acc[(k - 1) * 3 + 0] + bb2, 0.f);
            hsw[k * 192 + 1 * 64 + lane] = fmaxf(acc[(k - 1) * 3 + 1] + bb2, 0.f);
            hsw[k * 192 + 2 * 64 + lane] = fmaxf(acc[(k - 1) * 3 + 2] + bb2, 0.f);
        }
    }
    __builtin_amdgcn_wave_barrier();

    // ---- conv1: lane (pos,tc) computes c1[10+pos][tc] for the 4 slots ----
    // taps H[9+pos+k], k=0..2; pad tap (pos=1,k=2) killed via hCs weight scale.
    int pos = lane >> 5, tc = lane & 31;
    int pA = pos, pB = pos + 1, pC = (pos == 0) ? 2 : 0;
    float hCs = (pos == 0) ? 1.f : 0.f;
    float a1[4];
    float bc1 = b1c[tc];
#pragma unroll
    for (int r = 0; r < 4; ++r) a1[r] = bc1;
#pragma unroll
    for (int ic4 = 0; ic4 < 16; ++ic4) {
        float2 wa01 = w1s01[(ic4 * 4 + 0) * 32 + tc];
        float2 wb01 = w1s01[(ic4 * 4 + 1) * 32 + tc];
        float2 wc01 = w1s01[(ic4 * 4 + 2) * 32 + tc];
        float2 wd01 = w1s01[(ic4 * 4 + 3) * 32 + tc];
        float waz = w1s2[(ic4 * 4 + 0) * 32 + tc] * hCs;
        float wbz = w1s2[(ic4 * 4 + 1) * 32 + tc] * hCs;
        float wcz = w1s2[(ic4 * 4 + 2) * 32 + tc] * hCs;
        float wdz = w1s2[(ic4 * 4 + 3) * 32 + tc] * hCs;
#pragma unroll
        for (int r = 0; r < 4; ++r) {
            float4 hA = ((const float4*)&hsw[r * 192 + pA * 64])[ic4];
            float4 hB = ((const float4*)&hsw[r * 192 + pB * 64])[ic4];
            float4 hC = ((const float4*)&hsw[r * 192 + pC * 64])[ic4];
            a1[r] += hA.x * wa01.x + hB.x * wa01.y + hC.x * waz
                   + hA.y * wb01.x + hB.y * wb01.y + hC.y * wbz
                   + hA.z * wc01.x + hB.z * wc01.y + hC.z * wcz
                   + hA.w * wd01.x + hB.w * wd01.y + hC.w * wdz;
        }
    }
    __builtin_amdgcn_wave_barrier();   // all hs reads done before c1 alias-writes
    // c1(r,pos,tc) aliased at hsw[r*64 + pos*32 + tc] (first 256 floats of sm[wv])
#pragma unroll
    for (int r = 0; r < 4; ++r) hsw[r * 64 + pos * 32 + tc] = fmaxf(a1[r], 0.f);
    __builtin_amdgcn_wave_barrier();

    // ---- conv2 @ t=11 + relu + fc: half-wave pos handles slots {2pos, 2pos+1} ----
    int rr = pos * 2;
    float bc2 = b2c[tc];
    float a2q0 = bc2, a2q1 = bc2;
#pragma unroll
    for (int ic4 = 0; ic4 < 8; ++ic4) {
        float2 w0 = w2p[(ic4 * 4 + 0) * 32 + tc];
        float2 w1 = w2p[(ic4 * 4 + 1) * 32 + tc];
        float2 w2v = w2p[(ic4 * 4 + 2) * 32 + tc];
        float2 w3 = w2p[(ic4 * 4 + 3) * 32 + tc];
        float4 cA0 = ((const float4*)&hsw[(rr + 0) * 64 + 0])[ic4];
        float4 cB0 = ((const float4*)&hsw[(rr + 0) * 64 + 32])[ic4];
        float4 cA1 = ((const float4*)&hsw[(rr + 1) * 64 + 0])[ic4];
        float4 cB1 = ((const float4*)&hsw[(rr + 1) * 64 + 32])[ic4];
        a2q0 += cA0.x * w0.x + cB0.x * w0.y + cA0.y * w1.x + cB0.y * w1.y
              + cA0.z * w2v.x + cB0.z * w2v.y + cA0.w * w3.x + cB0.w * w3.y;
        a2q1 += cA1.x * w0.x + cB1.x * w0.y + cA1.y * w1.x + cB1.y * w1.y
              + cA1.z * w2v.x + cB1.z * w2v.y + cA1.w * w3.x + cB1.w * w3.y;
    }
    float fw = fcw[tc];
    float r0v = fmaxf(a2q0, 0.f) * fw;
    float r1v = fmaxf(a2q1, 0.f) * fw;
#pragma unroll
    for (int off = 16; off > 0; off >>= 1) {
        r0v += __shfl_down(r0v, off, 32);   // reduce within half-wave
        r1v += __shfl_down(r1v, off, 32);
    }
    if (tc == 0) {
        float fb = fcb[0];
        out[w + (rr + 0) * N_NODES] = r0v + fb;
        out[w + (rr + 1) * N_NODES] = r1v + fb;
    }
}

extern "C" void kernel_launch(void* const* d_in, const int* in_sizes, int n_in,
                              void* d_out, int out_size, void* d_ws, size_t ws_size,
                              hipStream_t stream) {
    const float* x   = (const float*)d_in[0];
    const int*   ei  = (const int*)d_in[1];
    const float* W1  = (const float*)d_in[2];
    const float* b1  = (const float*)d_in[3];
    const float* W2  = (const float*)d_in[4];
    const float* b2  = (const float*)d_in[5];
    const float* c1w = (const float*)d_in[6];
    const float* c1b = (const float*)d_in[7];
    const float* c2w = (const float*)d_in[8];
    const float* c2b = (const float*)d_in[9];
    const float* fcw = (const float*)d_in[10];
    const float* fcb = (const float*)d_in[11];
    float* out = (float*)d_out;

    const int E = in_sizes[1] / 2;
    const int* src = ei;
    const int* dst = ei + E;

    // ---- workspace layout (only mB remains, 7.7 MB) ----
    const size_t SG = (size_t)N_NODES * RSTRIDE;
    int*    cnt      = (int*)d_ws;                 // 10240
    int*    row_ptr  = cnt + 10240;                // 10240
    int*    fill_pos = row_ptr + 10240;            // 10240
    int2*   edges    = (int2*)(fill_pos + 10240);  // E records
    float*  dinv     = (float*)(edges + E);        // 10240
    float4* w1p      = (float4*)(dinv + 10240);    // 2048 float4 (16B-aligned)
    float2* w2p      = (float2*)(w1p + 2048);      // 1024 float2
    float*  mB       = (float*)(w2p + 1024);       // SG

    // ---- CSR build + weight packing ----
    hipMemsetAsync(cnt, 0, N_NODES * sizeof(int), stream);
    hist_kernel<<<(E + 255) / 256, 256, 0, stream>>>(dst, cnt, E);
    scan_kernel<<<1, 1024, 0, stream>>>(cnt, row_ptr, fill_pos, dinv);
    fill_kernel<<<(E + 255) / 256, 256, 0, stream>>>(src, dst, dinv, fill_pos, edges, E);
    prep_kernel<<<12, 256, 0, stream>>>(c1w, c2w, w1p, w2p);

    // ---- graph layer 1: x-gather (linearity) + W1 + relu + W2 -> mB ----
    gatherX_kernel<<<(N_NODES * HID) / 256, 256, 0, stream>>>(x, row_ptr, edges, dinv,
                                                              W1, b1, W2, mB);

    // ---- fused: layer-2 plane-phased gather + dense chain + conv + fc ----
    convfc_kernel<<<N_NODES / 8, 512, 0, stream>>>(mB, row_ptr, edges, dinv, b2,
                                                   x, W1, b1, W2,
                                                   w1p, c1b, w2p, c2b, fcw, fcb, out);
}

// Round 19
// 138.976 us; speedup vs baseline: 1.0481x; 1.0481x over previous
//
#include <hip/hip_runtime.h>

#define N_NODES 10000
#define BN_TOT  40000
#define HID     64
#define IN_F    16
#define TCH     32
#define NW      12
#define RSTRIDE 192   // floats per mB row: planes [t=3][ch=64] at +0B, +256B, +512B

// ---------------- histogram of dst (degree = cnt + 1) ------------------------
__global__ void hist_kernel(const int* __restrict__ dst, int* __restrict__ cnt, int E) {
    int e = blockIdx.x * blockDim.x + threadIdx.x;
    if (e < E) atomicAdd(&cnt[dst[e]], 1);
}

// ------ single-block scan, shuffle-based (1 barrier instead of 21) -----------
__global__ __launch_bounds__(1024) void scan_kernel(const int* __restrict__ cnt,
                                                    int* __restrict__ row_ptr,
                                                    int* __restrict__ fill_pos,
                                                    float* __restrict__ dinv) {
    __shared__ int wsum[16];
    int t = threadIdx.x;
    int lane = t & 63, wv = t >> 6;
    int base = t * 10;                       // 1024*10 = 10240 >= 10000
    int cl[10];
    int s = 0;
#pragma unroll
    for (int k = 0; k < 10; ++k) {
        int b = base + k;
        int c = (b < N_NODES) ? cnt[b] : 0;
        cl[k] = c; s += c;
    }
    // inclusive shuffle scan within wave
    int v = s;
#pragma unroll
    for (int off = 1; off < 64; off <<= 1) {
        int u = __shfl_up(v, off);
        if (lane >= off) v += u;
    }
    if (lane == 63) wsum[wv] = v;
    __syncthreads();
    int woff = 0;
    for (int i = 0; i < wv; ++i) woff += wsum[i];   // LDS broadcast reads
    int running = woff + v - s;                      // exclusive start of chunk
#pragma unroll
    for (int k = 0; k < 10; ++k) {
        int b = base + k;
        if (b < N_NODES) {
            row_ptr[b]  = running;
            fill_pos[b] = running;
            dinv[b] = rsqrtf((float)cl[k] + 1.0f);
            running += cl[k];
        }
    }
    if (t == 1023) row_ptr[N_NODES] = woff + v;
}

// ------ CSR bucket fill: edge record = {src*64 (byte off in x plane), ne} ----
__global__ void fill_kernel(const int* __restrict__ src, const int* __restrict__ dst,
                            const float* __restrict__ dinv,
                            int* __restrict__ fill_pos,
                            int2* __restrict__ edges, int E) {
    int e = blockIdx.x * blockDim.x + threadIdx.x;
    if (e >= E) return;
    int s = src[e], d = dst[e];
    int pos = atomicAdd(&fill_pos[d], 1);
    edges[pos] = make_int2(s * 64, __float_as_int(dinv[s] * dinv[d]));
}

// ---------------- pack conv weights: float4 / float2 per (ic, tc) ------------
__global__ void prep_kernel(const float* __restrict__ c1w, const float* __restrict__ c2w,
                            float4* __restrict__ w1p, float2* __restrict__ w2p) {
    int idx = blockIdx.x * blockDim.x + threadIdx.x;   // 3072 threads
    if (idx < 2048) {
        int tc = idx & 31, ic = idx >> 5;
        const float* p = c1w + tc * 192 + ic * 3;
        w1p[idx] = make_float4(p[0], p[1], p[2], 0.f);
    } else {
        int i2 = idx - 2048;
        int tc = i2 & 31, ic = i2 >> 5;
        const float* p = c2w + tc * 96 + ic * 3;
        w2p[i2] = make_float2(p[0], p[1]);
    }
}

// ---- gatherX (rows < N_NODES): xagg = Σ ne·x[src] + dinv²·x[dst]  (layer-1 --
// gather pushed through W1 by linearity). Then h1 = relu(xagg@W1 + b1);
// mB = h1 @ W2. Per edge: ONE 4B/lane load (48 active lanes, 192 B) + 1 FMA.
__global__ __launch_bounds__(256, 8) void gatherX_kernel(
        const float* __restrict__ x, const int* __restrict__ row_ptr,
        const int2* __restrict__ edges, const float* __restrict__ dinv,
        const float* __restrict__ W1, const float* __restrict__ b1,
        const float* __restrict__ W2, float* __restrict__ m2) {
    __shared__ float xs[4][64];       // aggregated x; slots 0..47 used
    __shared__ float hs[4][3][HID];
    int gid = blockIdx.x * blockDim.x + threadIdx.x;   // 10000 waves
    int lane = threadIdx.x & 63;
    int wv = threadIdx.x >> 6;
    int row = __builtin_amdgcn_readfirstlane(gid >> 6);
    int tt = lane >> 4; if (tt > 2) tt = 2;            // lanes 48-63 mirror t=2
    int f = lane & 15;
    const char* xlane = (const char*)(x + (size_t)(9 + tt) * N_NODES * IN_F + f);
    float dv = dinv[row];
    float s = dv * dv * *(const float*)(xlane + row * 64);
    int j = row_ptr[row], end = row_ptr[row + 1];
    for (; j + 7 < end; j += 8) {
        int2 e0 = edges[j],     e1 = edges[j + 1], e2 = edges[j + 2], e3 = edges[j + 3];
        int2 e4 = edges[j + 4], e5 = edges[j + 5], e6 = edges[j + 6], e7 = edges[j + 7];
        float v0 = *(const float*)(xlane + e0.x);
        float v1 = *(const float*)(xlane + e1.x);
        float v2 = *(const float*)(xlane + e2.x);
        float v3 = *(const float*)(xlane + e3.x);
        float v4 = *(const float*)(xlane + e4.x);
        float v5 = *(const float*)(xlane + e5.x);
        float v6 = *(const float*)(xlane + e6.x);
        float v7 = *(const float*)(xlane + e7.x);
        s += __int_as_float(e0.y) * v0 + __int_as_float(e1.y) * v1
           + __int_as_float(e2.y) * v2 + __int_as_float(e3.y) * v3
           + __int_as_float(e4.y) * v4 + __int_as_float(e5.y) * v5
           + __int_as_float(e6.y) * v6 + __int_as_float(e7.y) * v7;
    }
    for (; j < end; ++j) {
        int2 e = edges[j];
        s += __int_as_float(e.y) * *(const float*)(xlane + e.x);
    }
    xs[wv][lane] = s;                 // lanes 48-63 write dead slots
    __builtin_amdgcn_wave_barrier();

    // ---- W1 matmul: lane = oc; h1[t][oc] = relu(Σ_f xagg[t][f]·W1[f][oc]+b1)
    float w1r[16];
#pragma unroll
    for (int ff = 0; ff < IN_F; ++ff) w1r[ff] = W1[ff * HID + lane];
    float h0 = 0.f, h1v = 0.f, h2 = 0.f;
#pragma unroll
    for (int ff = 0; ff < IN_F; ++ff) {
        float wv1 = w1r[ff];
        h0  += wv1 * xs[wv][ff];
        h1v += wv1 * xs[wv][16 + ff];
        h2  += wv1 * xs[wv][32 + ff];
    }
    float bb = b1[lane];
    hs[wv][0][lane] = fmaxf(h0 + bb, 0.f);
    hs[wv][1][lane] = fmaxf(h1v + bb, 0.f);
    hs[wv][2][lane] = fmaxf(h2 + bb, 0.f);
    __builtin_amdgcn_wave_barrier();

    // ---- W2 matmul ----
    const float4* h0v4 = (const float4*)&hs[wv][0][0];
    const float4* h1v4 = (const float4*)&hs[wv][1][0];
    const float4* h2v4 = (const float4*)&hs[wv][2][0];
    float t0 = 0.f, t1 = 0.f, t2 = 0.f;
#pragma unroll
    for (int ic4 = 0; ic4 < 16; ++ic4) {
        float4 a0 = h0v4[ic4], a1 = h1v4[ic4], a2 = h2v4[ic4];
        float wA = W2[(ic4 * 4 + 0) * HID + lane];
        float wB = W2[(ic4 * 4 + 1) * HID + lane];
        float wC = W2[(ic4 * 4 + 2) * HID + lane];
        float wD = W2[(ic4 * 4 + 3) * HID + lane];
        t0 += a0.x * wA + a0.y * wB + a0.z * wC + a0.w * wD;
        t1 += a1.x * wA + a1.y * wB + a1.z * wC + a1.w * wD;
        t2 += a2.x * wA + a2.y * wB + a2.z * wC + a2.w * wD;
    }
    float* m2r = m2 + (size_t)row * RSTRIDE;
    m2r[lane] = t0; m2r[64 + lane] = t1; m2r[128 + lane] = t2;
}

// ---- convfc: wave w handles rows {w, w+10k, w+20k, w+30k} -------------------
// Slot 0 = graph row: single-pass layer-2 gather over mB (plane loads,
// 4-edge unroll = 12 loads in flight — measured-best MLP form).
// Slots 1..3 = dense rows. LDS 48 KB -> 3 blocks/CU.
__global__ __launch_bounds__(512, 6) void convfc_kernel(
        const float* __restrict__ mB, const int* __restrict__ row_ptr,
        const int2* __restrict__ edges,
        const float* __restrict__ dinv, const float* __restrict__ b2,
        const float* __restrict__ x, const float* __restrict__ W1,
        const float* __restrict__ b1, const float* __restrict__ W2,
        const float4* __restrict__ w1p, const float* __restrict__ b1c,
        const float2* __restrict__ w2p, const float* __restrict__ b2c,
        const float* __restrict__ fcw, const float* __restrict__ fcb,
        float* __restrict__ out) {
    __shared__ float2 w1s01[2048];          // (k0,k1) weights  16 KB
    __shared__ float  w1s2[2048];           // k2 weights        8 KB
    __shared__ float  sm[8][768];           // hs[slot][plane][ch]; c1 aliased  24 KB
    int t = threadIdx.x;
#pragma unroll
    for (int i = 0; i < 4; ++i) {
        float4 wv4 = w1p[i * 512 + t];
        w1s01[i * 512 + t] = make_float2(wv4.x, wv4.y);
        w1s2[i * 512 + t] = wv4.z;
    }
    __syncthreads();

    int wv = t >> 6, lane = t & 63;
    int w = __builtin_amdgcn_readfirstlane(blockIdx.x * 8 + wv);   // 0..9999
    float* hsw = sm[wv];   // hs(slot,plane,ch) = hsw[slot*192 + plane*64 + ch]

    // ---- slot 0: graph row w — layer-2 edge gather over mB (single pass) ----
    {
        const int lo0 = lane * 4, lo1 = 256 + lane * 4, lo2 = 512 + lane * 4;
        const char* mrow = (const char*)mB + (size_t)w * (RSTRIDE * 4);
        float dv = dinv[w];
        float sn = dv * dv;
        float s0 = sn * *(const float*)(mrow + lo0);
        float s1 = sn * *(const float*)(mrow + lo1);
        float s2 = sn * *(const float*)(mrow + lo2);
        int j = row_ptr[w], end = row_ptr[w + 1];
        for (; j + 3 < end; j += 4) {
            int2 e0 = edges[j], e1 = edges[j + 1], e2 = edges[j + 2], e3 = edges[j + 3];
            const char* q0 = (const char*)mB + e0.x * 12;   // src*64*12 = src*768
            const char* q1 = (const char*)mB + e1.x * 12;
            const char* q2 = (const char*)mB + e2.x * 12;
            const char* q3 = (const char*)mB + e3.x * 12;
            float w0 = __int_as_float(e0.y), w1 = __int_as_float(e1.y);
            float w2 = __int_as_float(e2.y), w3 = __int_as_float(e3.y);
            s0 += w0 * *(const float*)(q0 + lo0) + w1 * *(const float*)(q1 + lo0)
                + w2 * *(const float*)(q2 + lo0) + w3 * *(const float*)(q3 + lo0);
            s1 += w0 * *(const float*)(q0 + lo1) + w1 * *(const float*)(q1 + lo1)
                + w2 * *(const float*)(q2 + lo1) + w3 * *(const float*)(q3 + lo1);
            s2 += w0 * *(const float*)(q0 + lo2) + w1 * *(const float*)(q1 + lo2)
                + w2 * *(const float*)(q2 + lo2) + w3 * *(const float*)(q3 + lo2);
        }
        for (; j < end; ++j) {
            int2 e = edges[j];
            const char* q = (const char*)mB + e.x * 12;
            float ww = __int_as_float(e.y);
            s0 += ww * *(const float*)(q + lo0);
            s1 += ww * *(const float*)(q + lo1);
            s2 += ww * *(const float*)(q + lo2);
        }
        float bb = b2[lane];
        hsw[0 * 192 + 0 * 64 + lane] = fmaxf(s0 + bb, 0.f);
        hsw[0 * 192 + 1 * 64 + lane] = fmaxf(s1 + bb, 0.f);
        hsw[0 * 192 + 2 * 64 + lane] = fmaxf(s2 + bb, 0.f);
    }

    // ---- slots 1..3: dense rows w + k*10000 (b = k), full chain from x ----
    {
        float w1r[16];
#pragma unroll
        for (int f = 0; f < IN_F; ++f) w1r[f] = W1[f * HID + lane];
        float s[9];
#pragma unroll
        for (int k = 1; k <= 3; ++k) {
#pragma unroll
            for (int tt = 0; tt < 3; ++tt) {
                const float* xp = x + ((size_t)(k * NW + 9 + tt) * N_NODES + w) * IN_F;
                float a = 0.f;
#pragma unroll
                for (int f = 0; f < IN_F; ++f) a += xp[f] * w1r[f];  // xp uniform -> s_loads
                s[(k - 1) * 3 + tt] = a;
            }
        }
        float bb1 = b1[lane];
#pragma unroll
        for (int k = 1; k <= 3; ++k) {
            hsw[k * 192 + 0 * 64 + lane] = fmaxf(s[(k - 1) * 3 + 0] + bb1, 0.f);
            hsw[k * 192 + 1 * 64 + lane] = fmaxf(s[(k - 1) * 3 + 1] + bb1, 0.f);
            hsw[k * 192 + 2 * 64 + lane] = fmaxf(s[(k - 1) * 3 + 2] + bb1, 0.f);
        }
        __builtin_amdgcn_wave_barrier();
        float acc[9];
#pragma unroll
        for (int mm = 0; mm < 9; ++mm) acc[mm] = 0.f;
#pragma unroll
        for (int k4 = 0; k4 < 16; ++k4) {
            float wA = W2[(k4 * 4 + 0) * HID + lane];
            float wB = W2[(k4 * 4 + 1) * HID + lane];
            float wC = W2[(k4 * 4 + 2) * HID + lane];
            float wD = W2[(k4 * 4 + 3) * HID + lane];
#pragma unroll
            for (int k = 1; k <= 3; ++k) {
#pragma unroll
                for (int tt = 0; tt < 3; ++tt) {
                    float4 h = ((const float4*)&hsw[k * 192 + tt * 64])[k4];  // broadcast
                    acc[(k - 1) * 3 + tt] += h.x * wA + h.y * wB + h.z * wC + h.w * wD;
                }
            }
        }
        __builtin_amdgcn_wave_barrier();
        float bb2 = b2[lane];
#pragma unroll
        for (int k = 1; k <= 3; ++k) {
            hsw[k * 192 + 0 * 64 + lane] = fmaxf(acc[(k - 1) * 3 + 0] + bb2, 0.f);
            hsw[k * 192 + 1 * 64 + lane] = fmaxf(acc[(k - 1) * 3 + 1] + bb2, 0.f);
            hsw[k * 192 + 2 * 64 + lane] = fmaxf(acc[(k - 1) * 3 + 2] + bb2, 0.f);
        }
    }
    __builtin_amdgcn_wave_barrier();

    // ---- conv1: lane (pos,tc) computes c1[10+pos][tc] for the 4 slots ----
    // taps H[9+pos+k], k=0..2; pad tap (pos=1,k=2) killed via hCs weight scale.
    int pos = lane >> 5, tc = lane & 31;
    int pA = pos, pB = pos + 1, pC = (pos == 0) ? 2 : 0;
    float hCs = (pos == 0) ? 1.f : 0.f;
    float a1[4];
    float bc1 = b1c[tc];
#pragma unroll
    for (int r = 0; r < 4; ++r) a1[r] = bc1;
#pragma unroll
    for (int ic4 = 0; ic4 < 16; ++ic4) {
        float2 wa01 = w1s01[(ic4 * 4 + 0) * 32 + tc];
        float2 wb01 = w1s01[(ic4 * 4 + 1) * 32 + tc];
        float2 wc01 = w1s01[(ic4 * 4 + 2) * 32 + tc];
        float2 wd01 = w1s01[(ic4 * 4 + 3) * 32 + tc];
        float waz = w1s2[(ic4 * 4 + 0) * 32 + tc] * hCs;
        float wbz = w1s2[(ic4 * 4 + 1) * 32 + tc] * hCs;
        float wcz = w1s2[(ic4 * 4 + 2) * 32 + tc] * hCs;
        float wdz = w1s2[(ic4 * 4 + 3) * 32 + tc] * hCs;
#pragma unroll
        for (int r = 0; r < 4; ++r) {
            float4 hA = ((const float4*)&hsw[r * 192 + pA * 64])[ic4];
            float4 hB = ((const float4*)&hsw[r * 192 + pB * 64])[ic4];
            float4 hC = ((const float4*)&hsw[r * 192 + pC * 64])[ic4];
            a1[r] += hA.x * wa01.x + hB.x * wa01.y + hC.x * waz
                   + hA.y * wb01.x + hB.y * wb01.y + hC.y * wbz
                   + hA.z * wc01.x + hB.z * wc01.y + hC.z * wcz
                   + hA.w * wd01.x + hB.w * wd01.y + hC.w * wdz;
        }
    }
    __builtin_amdgcn_wave_barrier();   // all hs reads done before c1 alias-writes
    // c1(r,pos,tc) aliased at hsw[r*64 + pos*32 + tc] (first 256 floats of sm[wv])
#pragma unroll
    for (int r = 0; r < 4; ++r) hsw[r * 64 + pos * 32 + tc] = fmaxf(a1[r], 0.f);
    __builtin_amdgcn_wave_barrier();

    // ---- conv2 @ t=11 + relu + fc: half-wave pos handles slots {2pos, 2pos+1} ----
    int rr = pos * 2;
    float bc2 = b2c[tc];
    float a2q0 = bc2, a2q1 = bc2;
#pragma unroll
    for (int ic4 = 0; ic4 < 8; ++ic4) {
        float2 w0 = w2p[(ic4 * 4 + 0) * 32 + tc];
        float2 w1 = w2p[(ic4 * 4 + 1) * 32 + tc];
        float2 w2v = w2p[(ic4 * 4 + 2) * 32 + tc];
        float2 w3 = w2p[(ic4 * 4 + 3) * 32 + tc];
        float4 cA0 = ((const float4*)&hsw[(rr + 0) * 64 + 0])[ic4];
        float4 cB0 = ((const float4*)&hsw[(rr + 0) * 64 + 32])[ic4];
        float4 cA1 = ((const float4*)&hsw[(rr + 1) * 64 + 0])[ic4];
        float4 cB1 = ((const float4*)&hsw[(rr + 1) * 64 + 32])[ic4];
        a2q0 += cA0.x * w0.x + cB0.x * w0.y + cA0.y * w1.x + cB0.y * w1.y
              + cA0.z * w2v.x + cB0.z * w2v.y + cA0.w * w3.x + cB0.w * w3.y;
        a2q1 += cA1.x * w0.x + cB1.x * w0.y + cA1.y * w1.x + cB1.y * w1.y
              + cA1.z * w2v.x + cB1.z * w2v.y + cA1.w * w3.x + cB1.w * w3.y;
    }
    float fw = fcw[tc];
    float r0v = fmaxf(a2q0, 0.f) * fw;
    float r1v = fmaxf(a2q1, 0.f) * fw;
#pragma unroll
    for (int off = 16; off > 0; off >>= 1) {
        r0v += __shfl_down(r0v, off, 32);   // reduce within half-wave
        r1v += __shfl_down(r1v, off, 32);
    }
    if (tc == 0) {
        float fb = fcb[0];
        out[w + (rr + 0) * N_NODES] = r0v + fb;
        out[w + (rr + 1) * N_NODES] = r1v + fb;
    }
}

extern "C" void kernel_launch(void* const* d_in, const int* in_sizes, int n_in,
                              void* d_out, int out_size, void* d_ws, size_t ws_size,
                              hipStream_t stream) {
    const float* x   = (const float*)d_in[0];
    const int*   ei  = (const int*)d_in[1];
    const float* W1  = (const float*)d_in[2];
    const float* b1  = (const float*)d_in[3];
    const float* W2  = (const float*)d_in[4];
    const float* b2  = (const float*)d_in[5];
    const float* c1w = (const float*)d_in[6];
    const float* c1b = (const float*)d_in[7];
    const float* c2w = (const float*)d_in[8];
    const float* c2b = (const float*)d_in[9];
    const float* fcw = (const float*)d_in[10];
    const float* fcb = (const float*)d_in[11];
    float* out = (float*)d_out;

    const int E = in_sizes[1] / 2;
    const int* src = ei;
    const int* dst = ei + E;

    // ---- workspace layout (only mB remains, 7.7 MB) ----
    const size_t SG = (size_t)N_NODES * RSTRIDE;
    int*    cnt      = (int*)d_ws;                 // 10240
    int*    row_ptr  = cnt + 10240;                // 10240
    int*    fill_pos = row_ptr + 10240;            // 10240
    int2*   edges    = (int2*)(fill_pos + 10240);  // E records
    float*  dinv     = (float*)(edges + E);        // 10240
    float4* w1p      = (float4*)(dinv + 10240);    // 2048 float4 (16B-aligned)
    float2* w2p      = (float2*)(w1p + 2048);      // 1024 float2
    float*  mB       = (float*)(w2p + 1024);       // SG

    // ---- CSR build + weight packing ----
    hipMemsetAsync(cnt, 0, N_NODES * sizeof(int), stream);
    hist_kernel<<<(E + 255) / 256, 256, 0, stream>>>(dst, cnt, E);
    scan_kernel<<<1, 1024, 0, stream>>>(cnt, row_ptr, fill_pos, dinv);
    fill_kernel<<<(E + 255) / 256, 256, 0, stream>>>(src, dst, dinv, fill_pos, edges, E);
    prep_kernel<<<12, 256, 0, stream>>>(c1w, c2w, w1p, w2p);

    // ---- graph layer 1: x-gather (linearity) + W1 + relu + W2 -> mB ----
    gatherX_kernel<<<(N_NODES * HID) / 256, 256, 0, stream>>>(x, row_ptr, edges, dinv,
                                                              W1, b1, W2, mB);

    // ---- fused: layer-2 gather (graph rows) + dense chain + conv + fc ----
    convfc_kernel<<<N_NODES / 8, 512, 0, stream>>>(mB, row_ptr, edges, dinv, b2,
                                                   x, W1, b1, W2,
                                                   w1p, c1b, w2p, c2b, fcw, fcb, out);
}

// Round 20
// 137.400 us; speedup vs baseline: 1.0601x; 1.0115x over previous
//
#include <hip/hip_runtime.h>

#define N_NODES 10000
#define BN_TOT  40000
#define HID     64
#define IN_F    16
#define TCH     32
#define NW      12
#define RSTRIDE 192   // floats per mB row: planes [t=3][ch=64] at +0B, +256B, +512B

// ---------------- histogram of dst (degree = cnt + 1) ------------------------
__global__ void hist_kernel(const int* __restrict__ dst, int* __restrict__ cnt, int E) {
    int e = blockIdx.x * blockDim.x + threadIdx.x;
    if (e < E) atomicAdd(&cnt[dst[e]], 1);
}

// ------ single-block scan (shuffle-based) + conv-weight packing fused --------
__global__ __launch_bounds__(1024) void scan_kernel(const int* __restrict__ cnt,
                                                    int* __restrict__ row_ptr,
                                                    int* __restrict__ fill_pos,
                                                    float* __restrict__ dinv,
                                                    const float* __restrict__ c1w,
                                                    const float* __restrict__ c2w,
                                                    float4* __restrict__ w1p,
                                                    float2* __restrict__ w2p) {
    __shared__ int wsum[16];
    int t = threadIdx.x;
    // ---- fused prep: pack conv weights (3072 independent elements) ----
#pragma unroll
    for (int it = 0; it < 3; ++it) {
        int idx = t + it * 1024;
        if (idx < 2048) {
            int tc = idx & 31, ic = idx >> 5;
            const float* p = c1w + tc * 192 + ic * 3;
            w1p[idx] = make_float4(p[0], p[1], p[2], 0.f);
        } else {
            int i2 = idx - 2048;
            int tc = i2 & 31, ic = i2 >> 5;
            const float* p = c2w + tc * 96 + ic * 3;
            w2p[i2] = make_float2(p[0], p[1]);
        }
    }
    // ---- scan ----
    int lane = t & 63, wv = t >> 6;
    int base = t * 10;                       // 1024*10 = 10240 >= 10000
    int cl[10];
    int s = 0;
#pragma unroll
    for (int k = 0; k < 10; ++k) {
        int b = base + k;
        int c = (b < N_NODES) ? cnt[b] : 0;
        cl[k] = c; s += c;
    }
    int v = s;
#pragma unroll
    for (int off = 1; off < 64; off <<= 1) {
        int u = __shfl_up(v, off);
        if (lane >= off) v += u;
    }
    if (lane == 63) wsum[wv] = v;
    __syncthreads();
    int woff = 0;
    for (int i = 0; i < wv; ++i) woff += wsum[i];
    int running = woff + v - s;              // exclusive start of chunk
#pragma unroll
    for (int k = 0; k < 10; ++k) {
        int b = base + k;
        if (b < N_NODES) {
            row_ptr[b]  = running;
            fill_pos[b] = running;
            dinv[b] = rsqrtf((float)cl[k] + 1.0f);
            running += cl[k];
        }
    }
    if (t == 1023) row_ptr[N_NODES] = woff + v;
}

// ------ CSR bucket fill: edge record = {src*64 (byte off in x plane), ne} ----
__global__ void fill_kernel(const int* __restrict__ src, const int* __restrict__ dst,
                            const float* __restrict__ dinv,
                            int* __restrict__ fill_pos,
                            int2* __restrict__ edges, int E) {
    int e = blockIdx.x * blockDim.x + threadIdx.x;
    if (e >= E) return;
    int s = src[e], d = dst[e];
    int pos = atomicAdd(&fill_pos[d], 1);
    edges[pos] = make_int2(s * 64, __float_as_int(dinv[s] * dinv[d]));
}

// ---- gatherX (rows < N_NODES): xagg = Σ ne·x[src] + dinv²·x[dst]  (layer-1 --
// gather pushed through W1 by linearity). Then h1 = relu(xagg@W1 + b1);
// mB = h1 @ W2. Per edge: ONE 4B/lane load (48 active lanes, 192 B) + 1 FMA.
__global__ __launch_bounds__(256, 8) void gatherX_kernel(
        const float* __restrict__ x, const int* __restrict__ row_ptr,
        const int2* __restrict__ edges, const float* __restrict__ dinv,
        const float* __restrict__ W1, const float* __restrict__ b1,
        const float* __restrict__ W2, float* __restrict__ m2) {
    __shared__ float xs[4][64];       // aggregated x; slots 0..47 used
    __shared__ float hs[4][3][HID];
    int gid = blockIdx.x * blockDim.x + threadIdx.x;   // 10000 waves
    int lane = threadIdx.x & 63;
    int wv = threadIdx.x >> 6;
    int row = __builtin_amdgcn_readfirstlane(gid >> 6);
    int tt = lane >> 4; if (tt > 2) tt = 2;            // lanes 48-63 mirror t=2
    int f = lane & 15;
    const char* xlane = (const char*)(x + (size_t)(9 + tt) * N_NODES * IN_F + f);
    float dv = dinv[row];
    float s = dv * dv * *(const float*)(xlane + row * 64);
    int j = row_ptr[row], end = row_ptr[row + 1];
    for (; j + 7 < end; j += 8) {
        int2 e0 = edges[j],     e1 = edges[j + 1], e2 = edges[j + 2], e3 = edges[j + 3];
        int2 e4 = edges[j + 4], e5 = edges[j + 5], e6 = edges[j + 6], e7 = edges[j + 7];
        float v0 = *(const float*)(xlane + e0.x);
        float v1 = *(const float*)(xlane + e1.x);
        float v2 = *(const float*)(xlane + e2.x);
        float v3 = *(const float*)(xlane + e3.x);
        float v4 = *(const float*)(xlane + e4.x);
        float v5 = *(const float*)(xlane + e5.x);
        float v6 = *(const float*)(xlane + e6.x);
        float v7 = *(const float*)(xlane + e7.x);
        s += __int_as_float(e0.y) * v0 + __int_as_float(e1.y) * v1
           + __int_as_float(e2.y) * v2 + __int_as_float(e3.y) * v3
           + __int_as_float(e4.y) * v4 + __int_as_float(e5.y) * v5
           + __int_as_float(e6.y) * v6 + __int_as_float(e7.y) * v7;
    }
    for (; j < end; ++j) {
        int2 e = edges[j];
        s += __int_as_float(e.y) * *(const float*)(xlane + e.x);
    }
    xs[wv][lane] = s;                 // lanes 48-63 write dead slots
    __builtin_amdgcn_wave_barrier();

    // ---- W1 matmul: lane = oc; h1[t][oc] = relu(Σ_f xagg[t][f]·W1[f][oc]+b1)
    float w1r[16];
#pragma unroll
    for (int ff = 0; ff < IN_F; ++ff) w1r[ff] = W1[ff * HID + lane];
    float h0 = 0.f, h1v = 0.f, h2 = 0.f;
#pragma unroll
    for (int ff = 0; ff < IN_F; ++ff) {
        float wv1 = w1r[ff];
        h0  += wv1 * xs[wv][ff];
        h1v += wv1 * xs[wv][16 + ff];
        h2  += wv1 * xs[wv][32 + ff];
    }
    float bb = b1[lane];
    hs[wv][0][lane] = fmaxf(h0 + bb, 0.f);
    hs[wv][1][lane] = fmaxf(h1v + bb, 0.f);
    hs[wv][2][lane] = fmaxf(h2 + bb, 0.f);
    __builtin_amdgcn_wave_barrier();

    // ---- W2 matmul ----
    const float4* h0v4 = (const float4*)&hs[wv][0][0];
    const float4* h1v4 = (const float4*)&hs[wv][1][0];
    const float4* h2v4 = (const float4*)&hs[wv][2][0];
    float t0 = 0.f, t1 = 0.f, t2 = 0.f;
#pragma unroll
    for (int ic4 = 0; ic4 < 16; ++ic4) {
        float4 a0 = h0v4[ic4], a1 = h1v4[ic4], a2 = h2v4[ic4];
        float wA = W2[(ic4 * 4 + 0) * HID + lane];
        float wB = W2[(ic4 * 4 + 1) * HID + lane];
        float wC = W2[(ic4 * 4 + 2) * HID + lane];
        float wD = W2[(ic4 * 4 + 3) * HID + lane];
        t0 += a0.x * wA + a0.y * wB + a0.z * wC + a0.w * wD;
        t1 += a1.x * wA + a1.y * wB + a1.z * wC + a1.w * wD;
        t2 += a2.x * wA + a2.y * wB + a2.z * wC + a2.w * wD;
    }
    float* m2r = m2 + (size_t)row * RSTRIDE;
    m2r[lane] = t0; m2r[64 + lane] = t1; m2r[128 + lane] = t2;
}

// ---- convfc: wave w handles rows {w, w+10k, w+20k, w+30k} -------------------
// Slot 0 = graph row: single-pass layer-2 gather over mB, 8-edge unroll
// (24 loads in flight). Slots 1..3 = dense rows. LDS 48 KB -> 3 blocks/CU.
__global__ __launch_bounds__(512, 6) void convfc_kernel(
        const float* __restrict__ mB, const int* __restrict__ row_ptr,
        const int2* __restrict__ edges,
        const float* __restrict__ dinv, const float* __restrict__ b2,
        const float* __restrict__ x, const float* __restrict__ W1,
        const float* __restrict__ b1, const float* __restrict__ W2,
        const float4* __restrict__ w1p, const float* __restrict__ b1c,
        const float2* __restrict__ w2p, const float* __restrict__ b2c,
        const float* __restrict__ fcw, const float* __restrict__ fcb,
        float* __restrict__ out) {
    __shared__ float2 w1s01[2048];          // (k0,k1) weights  16 KB
    __shared__ float  w1s2[2048];           // k2 weights        8 KB
    __shared__ float  sm[8][768];           // hs[slot][plane][ch]; c1 aliased  24 KB
    int t = threadIdx.x;
#pragma unroll
    for (int i = 0; i < 4; ++i) {
        float4 wv4 = w1p[i * 512 + t];
        w1s01[i * 512 + t] = make_float2(wv4.x, wv4.y);
        w1s2[i * 512 + t] = wv4.z;
    }
    __syncthreads();

    int wv = t >> 6, lane = t & 63;
    int w = __builtin_amdgcn_readfirstlane(blockIdx.x * 8 + wv);   // 0..9999
    float* hsw = sm[wv];   // hs(slot,plane,ch) = hsw[slot*192 + plane*64 + ch]

    // ---- slot 0: graph row w — layer-2 edge gather over mB, 8-edge unroll ----
    {
        const int lo0 = lane * 4, lo1 = 256 + lane * 4, lo2 = 512 + lane * 4;
        const char* mrow = (const char*)mB + (size_t)w * (RSTRIDE * 4);
        float dv = dinv[w];
        float sn = dv * dv;
        float s0 = sn * *(const float*)(mrow + lo0);
        float s1 = sn * *(const float*)(mrow + lo1);
        float s2 = sn * *(const float*)(mrow + lo2);
        int j = row_ptr[w], end = row_ptr[w + 1];
        for (; j + 7 < end; j += 8) {
            int2 e0 = edges[j],     e1 = edges[j + 1], e2 = edges[j + 2], e3 = edges[j + 3];
            int2 e4 = edges[j + 4], e5 = edges[j + 5], e6 = edges[j + 6], e7 = edges[j + 7];
            const char* q0 = (const char*)mB + e0.x * 12;   // src*64*12 = src*768
            const char* q1 = (const char*)mB + e1.x * 12;
            const char* q2 = (const char*)mB + e2.x * 12;
            const char* q3 = (const char*)mB + e3.x * 12;
            const char* q4 = (const char*)mB + e4.x * 12;
            const char* q5 = (const char*)mB + e5.x * 12;
            const char* q6 = (const char*)mB + e6.x * 12;
            const char* q7 = (const char*)mB + e7.x * 12;
            float w0 = __int_as_float(e0.y), w1 = __int_as_float(e1.y);
            float w2 = __int_as_float(e2.y), w3 = __int_as_float(e3.y);
            float w4 = __int_as_float(e4.y), w5 = __int_as_float(e5.y);
            float w6 = __int_as_float(e6.y), w7 = __int_as_float(e7.y);
            s0 += w0 * *(const float*)(q0 + lo0) + w1 * *(const float*)(q1 + lo0)
                + w2 * *(const float*)(q2 + lo0) + w3 * *(const float*)(q3 + lo0)
                + w4 * *(const float*)(q4 + lo0) + w5 * *(const float*)(q5 + lo0)
                + w6 * *(const float*)(q6 + lo0) + w7 * *(const float*)(q7 + lo0);
            s1 += w0 * *(const float*)(q0 + lo1) + w1 * *(const float*)(q1 + lo1)
                + w2 * *(const float*)(q2 + lo1) + w3 * *(const float*)(q3 + lo1)
                + w4 * *(const float*)(q4 + lo1) + w5 * *(const float*)(q5 + lo1)
                + w6 * *(const float*)(q6 + lo1) + w7 * *(const float*)(q7 + lo1);
            s2 += w0 * *(const float*)(q0 + lo2) + w1 * *(const float*)(q1 + lo2)
                + w2 * *(const float*)(q2 + lo2) + w3 * *(const float*)(q3 + lo2)
                + w4 * *(const float*)(q4 + lo2) + w5 * *(const float*)(q5 + lo2)
                + w6 * *(const float*)(q6 + lo2) + w7 * *(const float*)(q7 + lo2);
        }
        for (; j < end; ++j) {
            int2 e = edges[j];
            const char* q = (const char*)mB + e.x * 12;
            float ww = __int_as_float(e.y);
            s0 += ww * *(const float*)(q + lo0);
            s1 += ww * *(const float*)(q + lo1);
            s2 += ww * *(const float*)(q + lo2);
        }
        float bb = b2[lane];
        hsw[0 * 192 + 0 * 64 + lane] = fmaxf(s0 + bb, 0.f);
        hsw[0 * 192 + 1 * 64 + lane] = fmaxf(s1 + bb, 0.f);
        hsw[0 * 192 + 2 * 64 + lane] = fmaxf(s2 + bb, 0.f);
    }

    // ---- slots 1..3: dense rows w + k*10000 (b = k), full chain from x ----
    {
        float w1r[16];
#pragma unroll
        for (int f = 0; f < IN_F; ++f) w1r[f] = W1[f * HID + lane];
        float s[9];
#pragma unroll
        for (int k = 1; k <= 3; ++k) {
#pragma unroll
            for (int tt = 0; tt < 3; ++tt) {
                const float* xp = x + ((size_t)(k * NW + 9 + tt) * N_NODES + w) * IN_F;
                float a = 0.f;
#pragma unroll
                for (int f = 0; f < IN_F; ++f) a += xp[f] * w1r[f];  // xp uniform -> s_loads
                s[(k - 1) * 3 + tt] = a;
            }
        }
        float bb1 = b1[lane];
#pragma unroll
        for (int k = 1; k <= 3; ++k) {
            hsw[k * 192 + 0 * 64 + lane] = fmaxf(s[(k - 1) * 3 + 0] + bb1, 0.f);
            hsw[k * 192 + 1 * 64 + lane] = fmaxf(s[(k - 1) * 3 + 1] + bb1, 0.f);
            hsw[k * 192 + 2 * 64 + lane] = fmaxf(s[(k - 1) * 3 + 2] + bb1, 0.f);
        }
        __builtin_amdgcn_wave_barrier();
        float acc[9];
#pragma unroll
        for (int mm = 0; mm < 9; ++mm) acc[mm] = 0.f;
#pragma unroll
        for (int k4 = 0; k4 < 16; ++k4) {
            float wA = W2[(k4 * 4 + 0) * HID + lane];
            float wB = W2[(k4 * 4 + 1) * HID + lane];
            float wC = W2[(k4 * 4 + 2) * HID + lane];
            float wD = W2[(k4 * 4 + 3) * HID + lane];
#pragma unroll
            for (int k = 1; k <= 3; ++k) {
#pragma unroll
                for (int tt = 0; tt < 3; ++tt) {
                    float4 h = ((const float4*)&hsw[k * 192 + tt * 64])[k4];  // broadcast
                    acc[(k - 1) * 3 + tt] += h.x * wA + h.y * wB + h.z * wC + h.w * wD;
                }
            }
        }
        __builtin_amdgcn_wave_barrier();
        float bb2 = b2[lane];
#pragma unroll
        for (int k = 1; k <= 3; ++k) {
            hsw[k * 192 + 0 * 64 + lane] = fmaxf(acc[(k - 1) * 3 + 0] + bb2, 0.f);
            hsw[k * 192 + 1 * 64 + lane] = fmaxf(acc[(k - 1) * 3 + 1] + bb2, 0.f);
            hsw[k * 192 + 2 * 64 + lane] = fmaxf(acc[(k - 1) * 3 + 2] + bb2, 0.f);
        }
    }
    __builtin_amdgcn_wave_barrier();

    // ---- conv1: lane (pos,tc) computes c1[10+pos][tc] for the 4 slots ----
    // taps H[9+pos+k], k=0..2; pad tap (pos=1,k=2) killed via hCs weight scale.
    int pos = lane >> 5, tc = lane & 31;
    int pA = pos, pB = pos + 1, pC = (pos == 0) ? 2 : 0;
    float hCs = (pos == 0) ? 1.f : 0.f;
    float a1[4];
    float bc1 = b1c[tc];
#pragma unroll
    for (int r = 0; r < 4; ++r) a1[r] = bc1;
#pragma unroll
    for (int ic4 = 0; ic4 < 16; ++ic4) {
        float2 wa01 = w1s01[(ic4 * 4 + 0) * 32 + tc];
        float2 wb01 = w1s01[(ic4 * 4 + 1) * 32 + tc];
        float2 wc01 = w1s01[(ic4 * 4 + 2) * 32 + tc];
        float2 wd01 = w1s01[(ic4 * 4 + 3) * 32 + tc];
        float waz = w1s2[(ic4 * 4 + 0) * 32 + tc] * hCs;
        float wbz = w1s2[(ic4 * 4 + 1) * 32 + tc] * hCs;
        float wcz = w1s2[(ic4 * 4 + 2) * 32 + tc] * hCs;
        float wdz = w1s2[(ic4 * 4 + 3) * 32 + tc] * hCs;
#pragma unroll
        for (int r = 0; r < 4; ++r) {
            float4 hA = ((const float4*)&hsw[r * 192 + pA * 64])[ic4];
            float4 hB = ((const float4*)&hsw[r * 192 + pB * 64])[ic4];
            float4 hC = ((const float4*)&hsw[r * 192 + pC * 64])[ic4];
            a1[r] += hA.x * wa01.x + hB.x * wa01.y + hC.x * waz
                   + hA.y * wb01.x + hB.y * wb01.y + hC.y * wbz
                   + hA.z * wc01.x + hB.z * wc01.y + hC.z * wcz
                   + hA.w * wd01.x + hB.w * wd01.y + hC.w * wdz;
        }
    }
    __builtin_amdgcn_wave_barrier();   // all hs reads done before c1 alias-writes
    // c1(r,pos,tc) aliased at hsw[r*64 + pos*32 + tc] (first 256 floats of sm[wv])
#pragma unroll
    for (int r = 0; r < 4; ++r) hsw[r * 64 + pos * 32 + tc] = fmaxf(a1[r], 0.f);
    __builtin_amdgcn_wave_barrier();

    // ---- conv2 @ t=11 + relu + fc: half-wave pos handles slots {2pos, 2pos+1} ----
    int rr = pos * 2;
    float bc2 = b2c[tc];
    float a2q0 = bc2, a2q1 = bc2;
#pragma unroll
    for (int ic4 = 0; ic4 < 8; ++ic4) {
        float2 w0 = w2p[(ic4 * 4 + 0) * 32 + tc];
        float2 w1 = w2p[(ic4 * 4 + 1) * 32 + tc];
        float2 w2v = w2p[(ic4 * 4 + 2) * 32 + tc];
        float2 w3 = w2p[(ic4 * 4 + 3) * 32 + tc];
        float4 cA0 = ((const float4*)&hsw[(rr + 0) * 64 + 0])[ic4];
        float4 cB0 = ((const float4*)&hsw[(rr + 0) * 64 + 32])[ic4];
        float4 cA1 = ((const float4*)&hsw[(rr + 1) * 64 + 0])[ic4];
        float4 cB1 = ((const float4*)&hsw[(rr + 1) * 64 + 32])[ic4];
        a2q0 += cA0.x * w0.x + cB0.x * w0.y + cA0.y * w1.x + cB0.y * w1.y
              + cA0.z * w2v.x + cB0.z * w2v.y + cA0.w * w3.x + cB0.w * w3.y;
        a2q1 += cA1.x * w0.x + cB1.x * w0.y + cA1.y * w1.x + cB1.y * w1.y
              + cA1.z * w2v.x + cB1.z * w2v.y + cA1.w * w3.x + cB1.w * w3.y;
    }
    float fw = fcw[tc];
    float r0v = fmaxf(a2q0, 0.f) * fw;
    float r1v = fmaxf(a2q1, 0.f) * fw;
#pragma unroll
    for (int off = 16; off > 0; off >>= 1) {
        r0v += __shfl_down(r0v, off, 32);   // reduce within half-wave
        r1v += __shfl_down(r1v, off, 32);
    }
    if (tc == 0) {
        float fb = fcb[0];
        out[w + (rr + 0) * N_NODES] = r0v + fb;
        out[w + (rr + 1) * N_NODES] = r1v + fb;
    }
}

extern "C" void kernel_launch(void* const* d_in, const int* in_sizes, int n_in,
                              void* d_out, int out_size, void* d_ws, size_t ws_size,
                              hipStream_t stream) {
    const float* x   = (const float*)d_in[0];
    const int*   ei  = (const int*)d_in[1];
    const float* W1  = (const float*)d_in[2];
    const float* b1  = (const float*)d_in[3];
    const float* W2  = (const float*)d_in[4];
    const float* b2  = (const float*)d_in[5];
    const float* c1w = (const float*)d_in[6];
    const float* c1b = (const float*)d_in[7];
    const float* c2w = (const float*)d_in[8];
    const float* c2b = (const float*)d_in[9];
    const float* fcw = (const float*)d_in[10];
    const float* fcb = (const float*)d_in[11];
    float* out = (float*)d_out;

    const int E = in_sizes[1] / 2;
    const int* src = ei;
    const int* dst = ei + E;

    // ---- workspace layout (only mB remains, 7.7 MB) ----
    const size_t SG = (size_t)N_NODES * RSTRIDE;
    int*    cnt      = (int*)d_ws;                 // 10240
    int*    row_ptr  = cnt + 10240;                // 10240
    int*    fill_pos = row_ptr + 10240;            // 10240
    int2*   edges    = (int2*)(fill_pos + 10240);  // E records
    float*  dinv     = (float*)(edges + E);        // 10240
    float4* w1p      = (float4*)(dinv + 10240);    // 2048 float4 (16B-aligned)
    float2* w2p      = (float2*)(w1p + 2048);      // 1024 float2
    float*  mB       = (float*)(w2p + 1024);       // SG

    // ---- CSR build + fused weight packing ----
    hipMemsetAsync(cnt, 0, N_NODES * sizeof(int), stream);
    hist_kernel<<<(E + 255) / 256, 256, 0, stream>>>(dst, cnt, E);
    scan_kernel<<<1, 1024, 0, stream>>>(cnt, row_ptr, fill_pos, dinv, c1w, c2w, w1p, w2p);
    fill_kernel<<<(E + 255) / 256, 256, 0, stream>>>(src, dst, dinv, fill_pos, edges, E);

    // ---- graph layer 1: x-gather (linearity) + W1 + relu + W2 -> mB ----
    gatherX_kernel<<<(N_NODES * HID) / 256, 256, 0, stream>>>(x, row_ptr, edges, dinv,
                                                              W1, b1, W2, mB);

    // ---- fused: layer-2 gather (graph rows) + dense chain + conv + fc ----
    convfc_kernel<<<N_NODES / 8, 512, 0, stream>>>(mB, row_ptr, edges, dinv, b2,
                                                   x, W1, b1, W2,
                                                   w1p, c1b, w2p, c2b, fcw, fcb, out);
}

// Round 23
// 136.361 us; speedup vs baseline: 1.0682x; 1.0076x over previous
//
#include <hip/hip_runtime.h>

#define N_NODES 10000
#define BN_TOT  40000
#define HID     64
#define IN_F    16
#define TCH     32
#define NW      12
#define RSTRIDE 192   // floats per mB row: planes [t=3][ch=64] at +0B, +256B, +512B

// ---------------- histogram of dst (degree = cnt + 1) ------------------------
__global__ void hist_kernel(const int* __restrict__ dst, int* __restrict__ cnt, int E) {
    int e = blockIdx.x * blockDim.x + threadIdx.x;
    if (e < E) atomicAdd(&cnt[dst[e]], 1);
}

// ------ single-block scan (shuffle-based) + conv-weight packing fused --------
// Packs: w1q[ic*32+tc] = (k0,k1); w1k2[ic*32+tc] = k2; w2p[ic*32+tc] = (k0,k1).
__global__ __launch_bounds__(1024) void scan_kernel(const int* __restrict__ cnt,
                                                    int* __restrict__ row_ptr,
                                                    int* __restrict__ fill_pos,
                                                    float* __restrict__ dinv,
                                                    const float* __restrict__ c1w,
                                                    const float* __restrict__ c2w,
                                                    float2* __restrict__ w1q,
                                                    float* __restrict__ w1k2,
                                                    float2* __restrict__ w2p) {
    __shared__ int wsum[16];
    int t = threadIdx.x;
    // ---- fused prep: pack conv weights ----
#pragma unroll
    for (int it = 0; it < 3; ++it) {
        int idx = t + it * 1024;
        if (idx < 2048) {
            int tc = idx & 31, ic = idx >> 5;
            const float* p = c1w + tc * 192 + ic * 3;
            w1q[idx] = make_float2(p[0], p[1]);
            w1k2[idx] = p[2];
        } else {
            int i2 = idx - 2048;
            int tc = i2 & 31, ic = i2 >> 5;
            const float* p = c2w + tc * 96 + ic * 3;
            w2p[i2] = make_float2(p[0], p[1]);
        }
    }
    // ---- scan ----
    int lane = t & 63, wv = t >> 6;
    int base = t * 10;                       // 1024*10 = 10240 >= 10000
    int cl[10];
    int s = 0;
#pragma unroll
    for (int k = 0; k < 10; ++k) {
        int b = base + k;
        int c = (b < N_NODES) ? cnt[b] : 0;
        cl[k] = c; s += c;
    }
    int v = s;
#pragma unroll
    for (int off = 1; off < 64; off <<= 1) {
        int u = __shfl_up(v, off);
        if (lane >= off) v += u;
    }
    if (lane == 63) wsum[wv] = v;
    __syncthreads();
    int woff = 0;
    for (int i = 0; i < wv; ++i) woff += wsum[i];
    int running = woff + v - s;              // exclusive start of chunk
#pragma unroll
    for (int k = 0; k < 10; ++k) {
        int b = base + k;
        if (b < N_NODES) {
            row_ptr[b]  = running;
            fill_pos[b] = running;
            dinv[b] = rsqrtf((float)cl[k] + 1.0f);
            running += cl[k];
        }
    }
    if (t == 1023) row_ptr[N_NODES] = woff + v;
}

// ------ CSR bucket fill: edge record = {src*64 (byte off in x plane), ne} ----
__global__ void fill_kernel(const int* __restrict__ src, const int* __restrict__ dst,
                            const float* __restrict__ dinv,
                            int* __restrict__ fill_pos,
                            int2* __restrict__ edges, int E) {
    int e = blockIdx.x * blockDim.x + threadIdx.x;
    if (e >= E) return;
    int s = src[e], d = dst[e];
    int pos = atomicAdd(&fill_pos[d], 1);
    edges[pos] = make_int2(s * 64, __float_as_int(dinv[s] * dinv[d]));
}

// ---- gatherX (rows < N_NODES): xagg = Σ ne·x[src] + dinv²·x[dst]  (layer-1 --
// gather pushed through W1 by linearity). Then h1 = relu(xagg@W1 + b1);
// mB = h1 @ W2. Per edge: ONE 4B/lane load (48 active lanes, 192 B) + 1 FMA.
__global__ __launch_bounds__(256, 8) void gatherX_kernel(
        const float* __restrict__ x, const int* __restrict__ row_ptr,
        const int2* __restrict__ edges, const float* __restrict__ dinv,
        const float* __restrict__ W1, const float* __restrict__ b1,
        const float* __restrict__ W2, float* __restrict__ m2) {
    __shared__ float xs[4][64];       // aggregated x; slots 0..47 used
    __shared__ float hs[4][3][HID];
    int gid = blockIdx.x * blockDim.x + threadIdx.x;   // 10000 waves
    int lane = threadIdx.x & 63;
    int wv = threadIdx.x >> 6;
    int row = __builtin_amdgcn_readfirstlane(gid >> 6);
    int tt = lane >> 4; if (tt > 2) tt = 2;            // lanes 48-63 mirror t=2
    int f = lane & 15;
    const char* xlane = (const char*)(x + (size_t)(9 + tt) * N_NODES * IN_F + f);
    float dv = dinv[row];
    float s = dv * dv * *(const float*)(xlane + row * 64);
    int j = row_ptr[row], end = row_ptr[row + 1];
    for (; j + 7 < end; j += 8) {
        int2 e0 = edges[j],     e1 = edges[j + 1], e2 = edges[j + 2], e3 = edges[j + 3];
        int2 e4 = edges[j + 4], e5 = edges[j + 5], e6 = edges[j + 6], e7 = edges[j + 7];
        float v0 = *(const float*)(xlane + e0.x);
        float v1 = *(const float*)(xlane + e1.x);
        float v2 = *(const float*)(xlane + e2.x);
        float v3 = *(const float*)(xlane + e3.x);
        float v4 = *(const float*)(xlane + e4.x);
        float v5 = *(const float*)(xlane + e5.x);
        float v6 = *(const float*)(xlane + e6.x);
        float v7 = *(const float*)(xlane + e7.x);
        s += __int_as_float(e0.y) * v0 + __int_as_float(e1.y) * v1
           + __int_as_float(e2.y) * v2 + __int_as_float(e3.y) * v3
           + __int_as_float(e4.y) * v4 + __int_as_float(e5.y) * v5
           + __int_as_float(e6.y) * v6 + __int_as_float(e7.y) * v7;
    }
    for (; j < end; ++j) {
        int2 e = edges[j];
        s += __int_as_float(e.y) * *(const float*)(xlane + e.x);
    }
    xs[wv][lane] = s;                 // lanes 48-63 write dead slots
    __builtin_amdgcn_wave_barrier();

    // ---- W1 matmul: lane = oc; h1[t][oc] = relu(Σ_f xagg[t][f]·W1[f][oc]+b1)
    float w1r[16];
#pragma unroll
    for (int ff = 0; ff < IN_F; ++ff) w1r[ff] = W1[ff * HID + lane];
    float h0 = 0.f, h1v = 0.f, h2 = 0.f;
#pragma unroll
    for (int ff = 0; ff < IN_F; ++ff) {
        float wv1 = w1r[ff];
        h0  += wv1 * xs[wv][ff];
        h1v += wv1 * xs[wv][16 + ff];
        h2  += wv1 * xs[wv][32 + ff];
    }
    float bb = b1[lane];
    hs[wv][0][lane] = fmaxf(h0 + bb, 0.f);
    hs[wv][1][lane] = fmaxf(h1v + bb, 0.f);
    hs[wv][2][lane] = fmaxf(h2 + bb, 0.f);
    __builtin_amdgcn_wave_barrier();

    // ---- W2 matmul ----
    const float4* h0v4 = (const float4*)&hs[wv][0][0];
    const float4* h1v4 = (const float4*)&hs[wv][1][0];
    const float4* h2v4 = (const float4*)&hs[wv][2][0];
    float t0 = 0.f, t1 = 0.f, t2 = 0.f;
#pragma unroll
    for (int ic4 = 0; ic4 < 16; ++ic4) {
        float4 a0 = h0v4[ic4], a1 = h1v4[ic4], a2 = h2v4[ic4];
        float wA = W2[(ic4 * 4 + 0) * HID + lane];
        float wB = W2[(ic4 * 4 + 1) * HID + lane];
        float wC = W2[(ic4 * 4 + 2) * HID + lane];
        float wD = W2[(ic4 * 4 + 3) * HID + lane];
        t0 += a0.x * wA + a0.y * wB + a0.z * wC + a0.w * wD;
        t1 += a1.x * wA + a1.y * wB + a1.z * wC + a1.w * wD;
        t2 += a2.x * wA + a2.y * wB + a2.z * wC + a2.w * wD;
    }
    float* m2r = m2 + (size_t)row * RSTRIDE;
    m2r[lane] = t0; m2r[64 + lane] = t1; m2r[128 + lane] = t2;
}

// ---- convfc: wave w handles rows {w, w+10k, w+20k, w+30k} -------------------
// Slot 0 = graph row: single-pass layer-2 gather over mB, 8-edge unroll.
// Slots 1..3 = dense rows. LDS 40 KB (w1q 16K staged + sm 24K; k2 weights
// read from global, L1-resident 8 KB) -> 4 blocks/CU = 32 waves/CU.
__global__ __launch_bounds__(512, 8) void convfc_kernel(
        const float* __restrict__ mB, const int* __restrict__ row_ptr,
        const int2* __restrict__ edges,
        const float* __restrict__ dinv, const float* __restrict__ b2,
        const float* __restrict__ x, const float* __restrict__ W1,
        const float* __restrict__ b1, const float* __restrict__ W2,
        const float2* __restrict__ w1q, const float* __restrict__ w1k2,
        const float* __restrict__ b1c,
        const float2* __restrict__ w2p, const float* __restrict__ b2c,
        const float* __restrict__ fcw, const float* __restrict__ fcb,
        float* __restrict__ out) {
    __shared__ float2 w1s01[2048];          // (k0,k1) weights  16 KB
    __shared__ float  sm[8][768];           // hs[slot][plane][ch]; c1 aliased  24 KB
    int t = threadIdx.x;
#pragma unroll
    for (int i = 0; i < 4; ++i) w1s01[i * 512 + t] = w1q[i * 512 + t];
    __syncthreads();

    int wv = t >> 6, lane = t & 63;
    int w = __builtin_amdgcn_readfirstlane(blockIdx.x * 8 + wv);   // 0..9999
    float* hsw = sm[wv];   // hs(slot,plane,ch) = hsw[slot*192 + plane*64 + ch]

    // ---- slot 0: graph row w — layer-2 edge gather over mB, 8-edge unroll ----
    {
        const int lo0 = lane * 4, lo1 = 256 + lane * 4, lo2 = 512 + lane * 4;
        const char* mrow = (const char*)mB + (size_t)w * (RSTRIDE * 4);
        float dv = dinv[w];
        float sn = dv * dv;
        float s0 = sn * *(const float*)(mrow + lo0);
        float s1 = sn * *(const float*)(mrow + lo1);
        float s2 = sn * *(const float*)(mrow + lo2);
        int j = row_ptr[w], end = row_ptr[w + 1];
        for (; j + 7 < end; j += 8) {
            int2 e0 = edges[j],     e1 = edges[j + 1], e2 = edges[j + 2], e3 = edges[j + 3];
            int2 e4 = edges[j + 4], e5 = edges[j + 5], e6 = edges[j + 6], e7 = edges[j + 7];
            const char* q0 = (const char*)mB + e0.x * 12;   // src*64*12 = src*768
            const char* q1 = (const char*)mB + e1.x * 12;
            const char* q2 = (const char*)mB + e2.x * 12;
            const char* q3 = (const char*)mB + e3.x * 12;
            const char* q4 = (const char*)mB + e4.x * 12;
            const char* q5 = (const char*)mB + e5.x * 12;
            const char* q6 = (const char*)mB + e6.x * 12;
            const char* q7 = (const char*)mB + e7.x * 12;
            float w0 = __int_as_float(e0.y), w1 = __int_as_float(e1.y);
            float w2 = __int_as_float(e2.y), w3 = __int_as_float(e3.y);
            float w4 = __int_as_float(e4.y), w5 = __int_as_float(e5.y);
            float w6 = __int_as_float(e6.y), w7 = __int_as_float(e7.y);
            s0 += w0 * *(const float*)(q0 + lo0) + w1 * *(const float*)(q1 + lo0)
                + w2 * *(const float*)(q2 + lo0) + w3 * *(const float*)(q3 + lo0)
                + w4 * *(const float*)(q4 + lo0) + w5 * *(const float*)(q5 + lo0)
                + w6 * *(const float*)(q6 + lo0) + w7 * *(const float*)(q7 + lo0);
            s1 += w0 * *(const float*)(q0 + lo1) + w1 * *(const float*)(q1 + lo1)
                + w2 * *(const float*)(q2 + lo1) + w3 * *(const float*)(q3 + lo1)
                + w4 * *(const float*)(q4 + lo1) + w5 * *(const float*)(q5 + lo1)
                + w6 * *(const float*)(q6 + lo1) + w7 * *(const float*)(q7 + lo1);
            s2 += w0 * *(const float*)(q0 + lo2) + w1 * *(const float*)(q1 + lo2)
                + w2 * *(const float*)(q2 + lo2) + w3 * *(const float*)(q3 + lo2)
                + w4 * *(const float*)(q4 + lo2) + w5 * *(const float*)(q5 + lo2)
                + w6 * *(const float*)(q6 + lo2) + w7 * *(const float*)(q7 + lo2);
        }
        for (; j < end; ++j) {
            int2 e = edges[j];
            const char* q = (const char*)mB + e.x * 12;
            float ww = __int_as_float(e.y);
            s0 += ww * *(const float*)(q + lo0);
            s1 += ww * *(const float*)(q + lo1);
            s2 += ww * *(const float*)(q + lo2);
        }
        float bb = b2[lane];
        hsw[0 * 192 + 0 * 64 + lane] = fmaxf(s0 + bb, 0.f);
        hsw[0 * 192 + 1 * 64 + lane] = fmaxf(s1 + bb, 0.f);
        hsw[0 * 192 + 2 * 64 + lane] = fmaxf(s2 + bb, 0.f);
    }

    // ---- slots 1..3: dense rows w + k*10000 (b = k), full chain from x ----
    {
        float w1r[16];
#pragma unroll
        for (int f = 0; f < IN_F; ++f) w1r[f] = W1[f * HID + lane];
        float s[9];
#pragma unroll
        for (int k = 1; k <= 3; ++k) {
#pragma unroll
            for (int tt = 0; tt < 3; ++tt) {
                const float* xp = x + ((size_t)(k * NW + 9 + tt) * N_NODES + w) * IN_F;
                float a = 0.f;
#pragma unroll
                for (int f = 0; f < IN_F; ++f) a += xp[f] * w1r[f];  // xp uniform -> s_loads
                s[(k - 1) * 3 + tt] = a;
            }
        }
        float bb1 = b1[lane];
#pragma unroll
        for (int k = 1; k <= 3; ++k) {
            hsw[k * 192 + 0 * 64 + lane] = fmaxf(s[(k - 1) * 3 + 0] + bb1, 0.f);
            hsw[k * 192 + 1 * 64 + lane] = fmaxf(s[(k - 1) * 3 + 1] + bb1, 0.f);
            hsw[k * 192 + 2 * 64 + lane] = fmaxf(s[(k - 1) * 3 + 2] + bb1, 0.f);
        }
        __builtin_amdgcn_wave_barrier();
        float acc[9];
#pragma unroll
        for (int mm = 0; mm < 9; ++mm) acc[mm] = 0.f;
#pragma unroll
        for (int k4 = 0; k4 < 16; ++k4) {
            float wA = W2[(k4 * 4 + 0) * HID + lane];
            float wB = W2[(k4 * 4 + 1) * HID + lane];
            float wC = W2[(k4 * 4 + 2) * HID + lane];
            float wD = W2[(k4 * 4 + 3) * HID + lane];
#pragma unroll
            for (int k = 1; k <= 3; ++k) {
#pragma unroll
                for (int tt = 0; tt < 3; ++tt) {
                    float4 h = ((const float4*)&hsw[k * 192 + tt * 64])[k4];  // broadcast
                    acc[(k - 1) * 3 + tt] += h.x * wA + h.y * wB + h.z * wC + h.w * wD;
                }
            }
        }
        __builtin_amdgcn_wave_barrier();
        float bb2 = b2[lane];
#pragma unroll
        for (int k = 1; k <= 3; ++k) {
            hsw[k * 192 + 0 * 64 + lane] = fmaxf(acc[(k - 1) * 3 + 0] + bb2, 0.f);
            hsw[k * 192 + 1 * 64 + lane] = fmaxf(acc[(k - 1) * 3 + 1] + bb2, 0.f);
            hsw[k * 192 + 2 * 64 + lane] = fmaxf(acc[(k - 1) * 3 + 2] + bb2, 0.f);
        }
    }
    __builtin_amdgcn_wave_barrier();

    // ---- conv1: lane (pos,tc) computes c1[10+pos][tc] for the 4 slots ----
    // k0,k1 weights from LDS; k2 weights from global (8 KB, L1-resident),
    // scaled by hCs to kill the pad tap at pos=1.
    int pos = lane >> 5, tc = lane & 31;
    int pA = pos, pB = pos + 1, pC = (pos == 0) ? 2 : 0;
    float hCs = (pos == 0) ? 1.f : 0.f;
    float a1[4];
    float bc1 = b1c[tc];
#pragma unroll
    for (int r = 0; r < 4; ++r) a1[r] = bc1;
#pragma unroll
    for (int ic4 = 0; ic4 < 16; ++ic4) {
        float2 wa01 = w1s01[(ic4 * 4 + 0) * 32 + tc];
        float2 wb01 = w1s01[(ic4 * 4 + 1) * 32 + tc];
        float2 wc01 = w1s01[(ic4 * 4 + 2) * 32 + tc];
        float2 wd01 = w1s01[(ic4 * 4 + 3) * 32 + tc];
        float waz = w1k2[(ic4 * 4 + 0) * 32 + tc] * hCs;
        float wbz = w1k2[(ic4 * 4 + 1) * 32 + tc] * hCs;
        float wcz = w1k2[(ic4 * 4 + 2) * 32 + tc] * hCs;
        float wdz = w1k2[(ic4 * 4 + 3) * 32 + tc] * hCs;
#pragma unroll
        for (int r = 0; r < 4; ++r) {
            float4 hA = ((const float4*)&hsw[r * 192 + pA * 64])[ic4];
            float4 hB = ((const float4*)&hsw[r * 192 + pB * 64])[ic4];
            float4 hC = ((const float4*)&hsw[r * 192 + pC * 64])[ic4];
            a1[r] += hA.x * wa01.x + hB.x * wa01.y + hC.x * waz
                   + hA.y * wb01.x + hB.y * wb01.y + hC.y * wbz
                   + hA.z * wc01.x + hB.z * wc01.y + hC.z * wcz
                   + hA.w * wd01.x + hB.w * wd01.y + hC.w * wdz;
        }
    }
    __builtin_amdgcn_wave_barrier();   // all hs reads done before c1 alias-writes
    // c1(r,pos,tc) aliased at hsw[r*64 + pos*32 + tc] (first 256 floats of sm[wv])
#pragma unroll
    for (int r = 0; r < 4; ++r) hsw[r * 64 + pos * 32 + tc] = fmaxf(a1[r], 0.f);
    __builtin_amdgcn_wave_barrier();

    // ---- conv2 @ t=11 + relu + fc: half-wave pos handles slots {2pos, 2pos+1} ----
    int rr = pos * 2;
    float bc2 = b2c[tc];
    float a2q0 = bc2, a2q1 = bc2;
#pragma unroll
    for (int ic4 = 0; ic4 < 8; ++ic4) {
        float2 w0 = w2p[(ic4 * 4 + 0) * 32 + tc];
        float2 w1 = w2p[(ic4 * 4 + 1) * 32 + tc];
        float2 w2v = w2p[(ic4 * 4 + 2) * 32 + tc];
        float2 w3 = w2p[(ic4 * 4 + 3) * 32 + tc];
        float4 cA0 = ((const float4*)&hsw[(rr + 0) * 64 + 0])[ic4];
        float4 cB0 = ((const float4*)&hsw[(rr + 0) * 64 + 32])[ic4];
        float4 cA1 = ((const float4*)&hsw[(rr + 1) * 64 + 0])[ic4];
        float4 cB1 = ((const float4*)&hsw[(rr + 1) * 64 + 32])[ic4];
        a2q0 += cA0.x * w0.x + cB0.x * w0.y + cA0.y * w1.x + cB0.y * w1.y
              + cA0.z * w2v.x + cB0.z * w2v.y + cA0.w * w3.x + cB0.w * w3.y;
        a2q1 += cA1.x * w0.x + cB1.x * w0.y + cA1.y * w1.x + cB1.y * w1.y
              + cA1.z * w2v.x + cB1.z * w2v.y + cA1.w * w3.x + cB1.w * w3.y;
    }
    float fw = fcw[tc];
    float r0v = fmaxf(a2q0, 0.f) * fw;
    float r1v = fmaxf(a2q1, 0.f) * fw;
#pragma unroll
    for (int off = 16; off > 0; off >>= 1) {
        r0v += __shfl_down(r0v, off, 32);   // reduce within half-wave
        r1v += __shfl_down(r1v, off, 32);
    }
    if (tc == 0) {
        float fb = fcb[0];
        out[w + (rr + 0) * N_NODES] = r0v + fb;
        out[w + (rr + 1) * N_NODES] = r1v + fb;
    }
}

extern "C" void kernel_launch(void* const* d_in, const int* in_sizes, int n_in,
                              void* d_out, int out_size, void* d_ws, size_t ws_size,
                              hipStream_t stream) {
    const float* x   = (const float*)d_in[0];
    const int*   ei  = (const int*)d_in[1];
    const float* W1  = (const float*)d_in[2];
    const float* b1  = (const float*)d_in[3];
    const float* W2  = (const float*)d_in[4];
    const float* b2  = (const float*)d_in[5];
    const float* c1w = (const float*)d_in[6];
    const float* c1b = (const float*)d_in[7];
    const float* c2w = (const float*)d_in[8];
    const float* c2b = (const float*)d_in[9];
    const float* fcw = (const float*)d_in[10];
    const float* fcb = (const float*)d_in[11];
    float* out = (float*)d_out;

    const int E = in_sizes[1] / 2;
    const int* src = ei;
    const int* dst = ei + E;

    // ---- workspace layout (only mB remains, 7.7 MB) ----
    const size_t SG = (size_t)N_NODES * RSTRIDE;
    int*    cnt      = (int*)d_ws;                 // 10240
    int*    row_ptr  = cnt + 10240;                // 10240
    int*    fill_pos = row_ptr + 10240;            // 10240
    int2*   edges    = (int2*)(fill_pos + 10240);  // E records (8B-aligned)
    float*  dinv     = (float*)(edges + E);        // 10240
    float2* w1q      = (float2*)(dinv + 10240);    // 2048 float2 (8B-aligned)
    float*  w1k2     = (float*)(w1q + 2048);       // 2048 floats
    float2* w2p      = (float2*)(w1k2 + 2048);     // 1024 float2
    float*  mB       = (float*)(w2p + 1024);       // SG

    // ---- CSR build + fused weight packing ----
    hipMemsetAsync(cnt, 0, N_NODES * sizeof(int), stream);
    hist_kernel<<<(E + 255) / 256, 256, 0, stream>>>(dst, cnt, E);
    scan_kernel<<<1, 1024, 0, stream>>>(cnt, row_ptr, fill_pos, dinv,
                                        c1w, c2w, w1q, w1k2, w2p);
    fill_kernel<<<(E + 255) / 256, 256, 0, stream>>>(src, dst, dinv, fill_pos, edges, E);

    // ---- graph layer 1: x-gather (linearity) + W1 + relu + W2 -> mB ----
    gatherX_kernel<<<(N_NODES * HID) / 256, 256, 0, stream>>>(x, row_ptr, edges, dinv,
                                                              W1, b1, W2, mB);

    // ---- fused: layer-2 gather (graph rows) + dense chain + conv + fc ----
    convfc_kernel<<<N_NODES / 8, 512, 0, stream>>>(mB, row_ptr, edges, dinv, b2,
                                                   x, W1, b1, W2,
                                                   w1q, w1k2, c1b, w2p, c2b, fcw, fcb, out);
}